// Round 1
// baseline (1379.955 us; speedup 1.0000x reference)
//
#include <hip/hip_runtime.h>
#include <hip/hip_bf16.h>
#include <math.h>

// Problem constants (fixed by the reference)
#define NE   16      // experts
#define DDIM 1024    // embed dim
#define II   4096    // expert intermediate
#define ISD  2048    // shared intermediate
#define TT   4096    // tokens
#define CAP  512     // expert capacity

typedef __attribute__((ext_vector_type(8))) short short8;
typedef __attribute__((ext_vector_type(4))) float floatx4;

static __device__ __forceinline__ unsigned short f2b(float f){
  unsigned int x = __float_as_uint(f);
  return (unsigned short)((x + 0x7fffu + ((x >> 16) & 1u)) >> 16);  // RNE fp32->bf16
}

static __device__ __forceinline__ float gelu_exact(float x){
  return 0.5f * x * (1.0f + erff(x * 0.70710678118654752f));
}

// async 16B global -> LDS (m97 pattern; dest must be wave-uniform base + lane*16)
#define ASYNC_COPY16(gptr, lptr)                                                    \
  __builtin_amdgcn_global_load_lds((const __attribute__((address_space(1))) void*)(gptr), \
                                   (__attribute__((address_space(3))) void*)(lptr), \
                                   16, 0, 0)

// ---------------- gating: fp64 logits + softmax -> scores (E,T) fp32 ----------------
__global__ void gating_kernel(const float* __restrict__ x, const float* __restrict__ gw,
                              float* __restrict__ scores){
  const int wave = threadIdx.x >> 6, lane = threadIdx.x & 63;
  const int t = blockIdx.x * 4 + wave;
  const float* xp = x + (size_t)t * DDIM;
  float xr[16];
  #pragma unroll
  for (int i = 0; i < 16; i++) xr[i] = xp[i * 64 + lane];
  double logit[NE];
  #pragma unroll
  for (int e = 0; e < NE; e++){
    const float* g = gw + (size_t)e * DDIM;
    double s = 0.0;
    #pragma unroll
    for (int i = 0; i < 16; i++) s += (double)xr[i] * (double)g[i * 64 + lane];
    #pragma unroll
    for (int off = 32; off > 0; off >>= 1) s += __shfl_xor(s, off);
    logit[e] = s;
  }
  double m = logit[0];
  #pragma unroll
  for (int e = 1; e < NE; e++) m = fmax(m, logit[e]);
  double p[NE], sum = 0.0;
  #pragma unroll
  for (int e = 0; e < NE; e++){ p[e] = exp(logit[e] - m); sum += p[e]; }
  if (lane == 0){
    #pragma unroll
    for (int e = 0; e < NE; e++) scores[(size_t)e * TT + t] = (float)(p[e] / sum);
  }
}

// ---------------- top-k by rank counting (matches lax.top_k set semantics) ----------------
__global__ void topk_kernel(const float* __restrict__ scores, int* __restrict__ cnt,
                            int* __restrict__ tidx, float* __restrict__ tw){
  const int e = blockIdx.y;
  __shared__ float s[TT];
  const float* se = scores + (size_t)e * TT;
  for (int i = threadIdx.x; i < TT; i += 256) s[i] = se[i];
  __syncthreads();
  const int t = blockIdx.x * 256 + threadIdx.x;
  const float ms = s[t];
  int r = 0;
  const float4* s4 = reinterpret_cast<const float4*>(s);
  for (int j = 0; j < TT / 4; j++){
    float4 v = s4[j];
    int b = j * 4;
    r += (v.x > ms) || (v.x == ms && (b + 0) < t);
    r += (v.y > ms) || (v.y == ms && (b + 1) < t);
    r += (v.z > ms) || (v.z == ms && (b + 2) < t);
    r += (v.w > ms) || (v.w == ms && (b + 3) < t);
  }
  if (r < CAP){
    int p = atomicAdd(&cnt[e], 1);
    tidx[e * CAP + p] = t;
    tw[e * CAP + p]   = ms;
  }
}

// ---------------- fp32 -> bf16 bulk convert (memory-bound, vectorized) ----------------
__global__ void cvt_bf16_kernel(const float* __restrict__ src, unsigned short* __restrict__ dst,
                                int n4){
  int i = blockIdx.x * 256 + threadIdx.x;
  const int stride = gridDim.x * 256;
  const float4* s = reinterpret_cast<const float4*>(src);
  ushort4* d = reinterpret_cast<ushort4*>(dst);
  for (; i < n4; i += stride){
    float4 v = s[i];
    ushort4 o; o.x = f2b(v.x); o.y = f2b(v.y); o.z = f2b(v.z); o.w = f2b(v.w);
    d[i] = o;
  }
}

// ---------------- gather selected token rows (bf16 source) ----------------
__global__ void gather_b16_kernel(const unsigned short* __restrict__ xb,
                                  const int* __restrict__ tidx,
                                  unsigned short* __restrict__ Xg){
  const int ec = blockIdx.x;                 // 0 .. E*CAP-1
  const int tok = tidx[ec];
  const ushort4* src = reinterpret_cast<const ushort4*>(xb + (size_t)tok * DDIM);
  ushort4* dst = reinterpret_cast<ushort4*>(Xg + (size_t)ec * DDIM);
  dst[threadIdx.x] = src[threadIdx.x];
}

// ---------------- gather (fp32 source -> bf16), fallback path ----------------
__global__ void gather_kernel(const float* __restrict__ x, const int* __restrict__ tidx,
                              unsigned short* __restrict__ Xg){
  const int ec = blockIdx.x;
  const int tok = tidx[ec];
  const float4* src = reinterpret_cast<const float4*>(x + (size_t)tok * DDIM);
  ushort4* dst = reinterpret_cast<ushort4*>(Xg + (size_t)ec * DDIM);
  float4 v = src[threadIdx.x];
  ushort4 o; o.x = f2b(v.x); o.y = f2b(v.y); o.z = f2b(v.z); o.w = f2b(v.w);
  dst[threadIdx.x] = o;
}

// ================= FAST PATH: pure-bf16 m97-structure GEMMs =================
// A: MxK bf16, Bg/Bu: NxK bf16, row-major. 128x128x32 tiles, global_load_lds staging.
__launch_bounds__(256, 2)
__global__ void gateup_bf16_kernel(const unsigned short* __restrict__ A,
                                   const unsigned short* __restrict__ Bg,
                                   const unsigned short* __restrict__ Bu,
                                   unsigned short* __restrict__ Hout,
                                   int M, int N, int K, long sA, long sB, long sH){
  __shared__ __align__(16) unsigned short As[128 * 32];
  __shared__ __align__(16) unsigned short Bgs[128 * 32];
  __shared__ __align__(16) unsigned short Bus[128 * 32];
  const int tid = threadIdx.x;
  const int z = blockIdx.z;
  A  += (size_t)z * sA;  Bg += (size_t)z * sB;  Bu += (size_t)z * sB;  Hout += (size_t)z * sH;
  const int bm = blockIdx.x * 128, bn = blockIdx.y * 128;  // m fastest -> B-tile L2 reuse
  const int lane = tid & 63, wave = tid >> 6;
  const int wr = wave >> 1, wc = wave & 1;
  const int fr = lane & 15, fq = lane >> 4;

  // staging geometry: thread tid covers dest bytes [tid*16, tid*16+16) of an 8 KiB tile
  const int srow = tid >> 2;            // 0..63 (rows per issue)
  const int scol = (tid & 3) * 8;       // bf16 elems
  const unsigned short* gA = A  + (size_t)(bm + srow) * K + scol;
  const unsigned short* gG = Bg + (size_t)(bn + srow) * K + scol;
  const unsigned short* gU = Bu + (size_t)(bn + srow) * K + scol;
  const size_t half = (size_t)64 * K;   // +64 rows for second issue
  unsigned short* lA = As  + tid * 8;   // lane-linear dest (required by global_load_lds)
  unsigned short* lG = Bgs + tid * 8;
  unsigned short* lU = Bus + tid * 8;

  floatx4 accG[4][4], accU[4][4];
  const floatx4 z4 = {0.f, 0.f, 0.f, 0.f};
  #pragma unroll
  for (int m = 0; m < 4; m++)
    #pragma unroll
    for (int n = 0; n < 4; n++){ accG[m][n] = z4; accU[m][n] = z4; }

  for (int k0 = 0; k0 < K; k0 += 32){
    ASYNC_COPY16(gA + k0,        lA);
    ASYNC_COPY16(gA + half + k0, lA + 2048);
    ASYNC_COPY16(gG + k0,        lG);
    ASYNC_COPY16(gG + half + k0, lG + 2048);
    ASYNC_COPY16(gU + k0,        lU);
    ASYNC_COPY16(gU + half + k0, lU + 2048);
    __syncthreads();
    short8 aF[4], gF[4], uF[4];
    #pragma unroll
    for (int m = 0; m < 4; m++)
      aF[m] = *reinterpret_cast<const short8*>(&As[(wr * 64 + m * 16 + fr) * 32 + fq * 8]);
    #pragma unroll
    for (int n = 0; n < 4; n++){
      gF[n] = *reinterpret_cast<const short8*>(&Bgs[(wc * 64 + n * 16 + fr) * 32 + fq * 8]);
      uF[n] = *reinterpret_cast<const short8*>(&Bus[(wc * 64 + n * 16 + fr) * 32 + fq * 8]);
    }
    #pragma unroll
    for (int m = 0; m < 4; m++)
      #pragma unroll
      for (int n = 0; n < 4; n++){
        accG[m][n] = __builtin_amdgcn_mfma_f32_16x16x32_bf16(aF[m], gF[n], accG[m][n], 0, 0, 0);
        accU[m][n] = __builtin_amdgcn_mfma_f32_16x16x32_bf16(aF[m], uF[n], accU[m][n], 0, 0, 0);
      }
    __syncthreads();
  }
  #pragma unroll
  for (int m = 0; m < 4; m++)
    #pragma unroll
    for (int n = 0; n < 4; n++){
      const int col  = bn + wc * 64 + n * 16 + fr;
      const int row0 = bm + wr * 64 + m * 16 + fq * 4;
      #pragma unroll
      for (int i = 0; i < 4; i++){
        float g = accG[m][n][i], u = accU[m][n][i];
        Hout[(size_t)(row0 + i) * N + col] = f2b(gelu_exact(g) * u);
      }
    }
}

template<int ATOMIC>
__launch_bounds__(256, 2)
__global__ void down_bf16_kernel(const unsigned short* __restrict__ A,
                                 const unsigned short* __restrict__ B,
                                 float* __restrict__ out,
                                 const int* __restrict__ tidx, const float* __restrict__ tw,
                                 int M, int N, int K, long sA, long sB){
  __shared__ __align__(16) unsigned short As[128 * 32];
  __shared__ __align__(16) unsigned short Bs[128 * 32];
  const int tid = threadIdx.x;
  const int z = blockIdx.z;
  A += (size_t)z * sA;  B += (size_t)z * sB;
  const int bm = blockIdx.x * 128, bn = blockIdx.y * 128;
  const int lane = tid & 63, wave = tid >> 6;
  const int wr = wave >> 1, wc = wave & 1;
  const int fr = lane & 15, fq = lane >> 4;

  const int srow = tid >> 2;
  const int scol = (tid & 3) * 8;
  const unsigned short* gA = A + (size_t)(bm + srow) * K + scol;
  const unsigned short* gB = B + (size_t)(bn + srow) * K + scol;
  const size_t half = (size_t)64 * K;
  unsigned short* lA = As + tid * 8;
  unsigned short* lB = Bs + tid * 8;

  floatx4 acc[4][4];
  const floatx4 z4 = {0.f, 0.f, 0.f, 0.f};
  #pragma unroll
  for (int m = 0; m < 4; m++)
    #pragma unroll
    for (int n = 0; n < 4; n++) acc[m][n] = z4;

  for (int k0 = 0; k0 < K; k0 += 32){
    ASYNC_COPY16(gA + k0,        lA);
    ASYNC_COPY16(gA + half + k0, lA + 2048);
    ASYNC_COPY16(gB + k0,        lB);
    ASYNC_COPY16(gB + half + k0, lB + 2048);
    __syncthreads();
    short8 aF[4], bF[4];
    #pragma unroll
    for (int m = 0; m < 4; m++)
      aF[m] = *reinterpret_cast<const short8*>(&As[(wr * 64 + m * 16 + fr) * 32 + fq * 8]);
    #pragma unroll
    for (int n = 0; n < 4; n++)
      bF[n] = *reinterpret_cast<const short8*>(&Bs[(wc * 64 + n * 16 + fr) * 32 + fq * 8]);
    #pragma unroll
    for (int m = 0; m < 4; m++)
      #pragma unroll
      for (int n = 0; n < 4; n++)
        acc[m][n] = __builtin_amdgcn_mfma_f32_16x16x32_bf16(aF[m], bF[n], acc[m][n], 0, 0, 0);
    __syncthreads();
  }
  #pragma unroll
  for (int m = 0; m < 4; m++)
    #pragma unroll
    for (int n = 0; n < 4; n++){
      const int col  = bn + wc * 64 + n * 16 + fr;
      const int row0 = bm + wr * 64 + m * 16 + fq * 4;
      #pragma unroll
      for (int i = 0; i < 4; i++){
        float val = acc[m][n][i];
        if constexpr (ATOMIC){
          const int r = row0 + i;
          const int token = tidx[z * CAP + r];
          const float wgt = tw[z * CAP + r];
          atomicAdd(&out[(size_t)token * DDIM + col], val * wgt);
        } else {
          out[(size_t)(row0 + i) * N + col] = val;
        }
      }
    }
}

// ================= FALLBACK PATH (verified previously): fp32-B staging =================
#define LDT 40
template<typename TA>
__launch_bounds__(256, 2)
__global__ void gateup_kernel(const TA* __restrict__ A, const float* __restrict__ Bg,
                              const float* __restrict__ Bu, unsigned short* __restrict__ H,
                              int M, int N, int K, long sA, long sB, long sH){
  __shared__ unsigned short As[128 * LDT];
  __shared__ unsigned short Bgs[128 * LDT];
  __shared__ unsigned short Bus[128 * LDT];
  const int tid = threadIdx.x;
  const int z = blockIdx.z;
  A  += (size_t)z * sA;  Bg += (size_t)z * sB;  Bu += (size_t)z * sB;  H += (size_t)z * sH;
  const int bm = blockIdx.x * 128, bn = blockIdx.y * 128;
  const int lane = tid & 63, wave = tid >> 6;
  const int wr = wave >> 1, wc = wave & 1;
  const int fr = lane & 15, fq = lane >> 4;

  floatx4 accG[4][4], accU[4][4];
  const floatx4 z4 = {0.f, 0.f, 0.f, 0.f};
  #pragma unroll
  for (int m = 0; m < 4; m++)
    #pragma unroll
    for (int n = 0; n < 4; n++){ accG[m][n] = z4; accU[m][n] = z4; }

  for (int k0 = 0; k0 < K; k0 += 32){
    #pragma unroll
    for (int p = 0; p < 4; p++){
      const int row = p * 32 + (tid >> 3);
      const int col = (tid & 7) * 4;
      if constexpr (__is_same(TA, float)){
        float4 v = *reinterpret_cast<const float4*>(A + (size_t)(bm + row) * K + k0 + col);
        ushort4 o; o.x = f2b(v.x); o.y = f2b(v.y); o.z = f2b(v.z); o.w = f2b(v.w);
        *reinterpret_cast<ushort4*>(&As[row * LDT + col]) = o;
      } else {
        *reinterpret_cast<ushort4*>(&As[row * LDT + col]) =
            *reinterpret_cast<const ushort4*>(A + (size_t)(bm + row) * K + k0 + col);
      }
      float4 vg = *reinterpret_cast<const float4*>(Bg + (size_t)(bn + row) * K + k0 + col);
      ushort4 og; og.x = f2b(vg.x); og.y = f2b(vg.y); og.z = f2b(vg.z); og.w = f2b(vg.w);
      *reinterpret_cast<ushort4*>(&Bgs[row * LDT + col]) = og;
      float4 vu = *reinterpret_cast<const float4*>(Bu + (size_t)(bn + row) * K + k0 + col);
      ushort4 ou; ou.x = f2b(vu.x); ou.y = f2b(vu.y); ou.z = f2b(vu.z); ou.w = f2b(vu.w);
      *reinterpret_cast<ushort4*>(&Bus[row * LDT + col]) = ou;
    }
    __syncthreads();
    short8 aF[4], gF[4], uF[4];
    #pragma unroll
    for (int m = 0; m < 4; m++)
      aF[m] = *reinterpret_cast<const short8*>(&As[(wr * 64 + m * 16 + fr) * LDT + fq * 8]);
    #pragma unroll
    for (int n = 0; n < 4; n++){
      gF[n] = *reinterpret_cast<const short8*>(&Bgs[(wc * 64 + n * 16 + fr) * LDT + fq * 8]);
      uF[n] = *reinterpret_cast<const short8*>(&Bus[(wc * 64 + n * 16 + fr) * LDT + fq * 8]);
    }
    #pragma unroll
    for (int m = 0; m < 4; m++)
      #pragma unroll
      for (int n = 0; n < 4; n++){
        accG[m][n] = __builtin_amdgcn_mfma_f32_16x16x32_bf16(aF[m], gF[n], accG[m][n], 0, 0, 0);
        accU[m][n] = __builtin_amdgcn_mfma_f32_16x16x32_bf16(aF[m], uF[n], accU[m][n], 0, 0, 0);
      }
    __syncthreads();
  }
  #pragma unroll
  for (int m = 0; m < 4; m++)
    #pragma unroll
    for (int n = 0; n < 4; n++){
      const int col  = bn + wc * 64 + n * 16 + fr;
      const int row0 = bm + wr * 64 + m * 16 + fq * 4;
      #pragma unroll
      for (int i = 0; i < 4; i++){
        float g = accG[m][n][i], u = accU[m][n][i];
        H[(size_t)(row0 + i) * N + col] = f2b(gelu_exact(g) * u);
      }
    }
}

template<int ATOMIC>
__launch_bounds__(256, 2)
__global__ void down_kernel(const unsigned short* __restrict__ A, const float* __restrict__ B,
                            float* __restrict__ out, const int* __restrict__ tidx,
                            const float* __restrict__ tw,
                            int M, int N, int K, long sA, long sB){
  __shared__ unsigned short As[128 * LDT];
  __shared__ unsigned short Bs[128 * LDT];
  const int tid = threadIdx.x;
  const int z = blockIdx.z;
  A += (size_t)z * sA;  B += (size_t)z * sB;
  const int bm = blockIdx.x * 128, bn = blockIdx.y * 128;
  const int lane = tid & 63, wave = tid >> 6;
  const int wr = wave >> 1, wc = wave & 1;
  const int fr = lane & 15, fq = lane >> 4;

  floatx4 acc[4][4];
  const floatx4 z4 = {0.f, 0.f, 0.f, 0.f};
  #pragma unroll
  for (int m = 0; m < 4; m++)
    #pragma unroll
    for (int n = 0; n < 4; n++) acc[m][n] = z4;

  for (int k0 = 0; k0 < K; k0 += 32){
    #pragma unroll
    for (int p = 0; p < 4; p++){
      const int row = p * 32 + (tid >> 3);
      const int col = (tid & 7) * 4;
      *reinterpret_cast<ushort4*>(&As[row * LDT + col]) =
          *reinterpret_cast<const ushort4*>(A + (size_t)(bm + row) * K + k0 + col);
      float4 v = *reinterpret_cast<const float4*>(B + (size_t)(bn + row) * K + k0 + col);
      ushort4 o; o.x = f2b(v.x); o.y = f2b(v.y); o.z = f2b(v.z); o.w = f2b(v.w);
      *reinterpret_cast<ushort4*>(&Bs[row * LDT + col]) = o;
    }
    __syncthreads();
    short8 aF[4], bF[4];
    #pragma unroll
    for (int m = 0; m < 4; m++)
      aF[m] = *reinterpret_cast<const short8*>(&As[(wr * 64 + m * 16 + fr) * LDT + fq * 8]);
    #pragma unroll
    for (int n = 0; n < 4; n++)
      bF[n] = *reinterpret_cast<const short8*>(&Bs[(wc * 64 + n * 16 + fr) * LDT + fq * 8]);
    #pragma unroll
    for (int m = 0; m < 4; m++)
      #pragma unroll
      for (int n = 0; n < 4; n++)
        acc[m][n] = __builtin_amdgcn_mfma_f32_16x16x32_bf16(aF[m], bF[n], acc[m][n], 0, 0, 0);
    __syncthreads();
  }
  #pragma unroll
  for (int m = 0; m < 4; m++)
    #pragma unroll
    for (int n = 0; n < 4; n++){
      const int col  = bn + wc * 64 + n * 16 + fr;
      const int row0 = bm + wr * 64 + m * 16 + fq * 4;
      #pragma unroll
      for (int i = 0; i < 4; i++){
        float val = acc[m][n][i];
        if constexpr (ATOMIC){
          const int r = row0 + i;
          const int token = tidx[z * CAP + r];
          const float wgt = tw[z * CAP + r];
          atomicAdd(&out[(size_t)token * DDIM + col], val * wgt);
        } else {
          out[(size_t)(row0 + i) * N + col] = val;
        }
      }
    }
}

extern "C" void kernel_launch(void* const* d_in, const int* in_sizes, int n_in,
                              void* d_out, int out_size, void* d_ws, size_t ws_size,
                              hipStream_t stream){
  const float* x  = (const float*)d_in[0];
  const float* gw = (const float*)d_in[1];
  const float* Wg = (const float*)d_in[2];
  const float* Wu = (const float*)d_in[3];
  const float* Wd = (const float*)d_in[4];
  const float* Sg = (const float*)d_in[5];
  const float* Su = (const float*)d_in[6];
  const float* Sd = (const float*)d_in[7];
  float* out = (float*)d_out;

  char* w = (char*)d_ws;
  float* scores        = (float*)w;           w += (size_t)NE * TT * 4;
  int*   cnt           = (int*)w;             w += 256;
  int*   tidx          = (int*)w;             w += (size_t)NE * CAP * 4;
  float* tw            = (float*)w;           w += (size_t)NE * CAP * 4;
  unsigned short* Xg   = (unsigned short*)w;  w += (size_t)NE * CAP * DDIM * 2;
  unsigned short* H    = (unsigned short*)w;  w += (size_t)NE * CAP * II * 2;
  unsigned short* Hs   = (unsigned short*)w;  w += (size_t)TT * ISD * 2;

  const size_t base_used = (size_t)(w - (char*)d_ws);
  const size_t need_extra = (size_t)TT * DDIM * 2           // xb
                          + (size_t)NE * II * DDIM * 2 * 2  // bWg, bWu
                          + (size_t)NE * DDIM * II * 2      // bWd
                          + (size_t)ISD * DDIM * 2 * 2      // bSg, bSu
                          + (size_t)DDIM * ISD * 2;         // bSd
  const bool fast = (base_used + need_extra) <= ws_size;    // ~525 MB total

  hipMemsetAsync(cnt, 0, NE * sizeof(int), stream);
  gating_kernel<<<TT / 4, 256, 0, stream>>>(x, gw, scores);
  topk_kernel<<<dim3(TT / 256, NE), 256, 0, stream>>>(scores, cnt, tidx, tw);

  if (fast){
    unsigned short* xb  = (unsigned short*)w;  w += (size_t)TT * DDIM * 2;
    unsigned short* bWg = (unsigned short*)w;  w += (size_t)NE * II * DDIM * 2;
    unsigned short* bWu = (unsigned short*)w;  w += (size_t)NE * II * DDIM * 2;
    unsigned short* bWd = (unsigned short*)w;  w += (size_t)NE * DDIM * II * 2;
    unsigned short* bSg = (unsigned short*)w;  w += (size_t)ISD * DDIM * 2;
    unsigned short* bSu = (unsigned short*)w;  w += (size_t)ISD * DDIM * 2;
    unsigned short* bSd = (unsigned short*)w;  w += (size_t)DDIM * ISD * 2;

    // one-time fp32 -> bf16 conversion (memory-bound, ~1.26 GB total traffic)
    cvt_bf16_kernel<<<1024, 256, 0, stream>>>(x,  xb,  TT * DDIM / 4);
    cvt_bf16_kernel<<<2048, 256, 0, stream>>>(Wg, bWg, NE * II * DDIM / 4);
    cvt_bf16_kernel<<<2048, 256, 0, stream>>>(Wu, bWu, NE * II * DDIM / 4);
    cvt_bf16_kernel<<<2048, 256, 0, stream>>>(Wd, bWd, NE * DDIM * II / 4);
    cvt_bf16_kernel<<<512, 256, 0, stream>>>(Sg, bSg, ISD * DDIM / 4);
    cvt_bf16_kernel<<<512, 256, 0, stream>>>(Su, bSu, ISD * DDIM / 4);
    cvt_bf16_kernel<<<512, 256, 0, stream>>>(Sd, bSd, DDIM * ISD / 4);

    gather_b16_kernel<<<NE * CAP, 256, 0, stream>>>(xb, tidx, Xg);

    // shared experts
    gateup_bf16_kernel<<<dim3(TT / 128, ISD / 128, 1), 256, 0, stream>>>(
        xb, bSg, bSu, Hs, TT, ISD, DDIM, 0, 0, 0);
    down_bf16_kernel<0><<<dim3(TT / 128, DDIM / 128, 1), 256, 0, stream>>>(
        Hs, bSd, out, nullptr, nullptr, TT, DDIM, ISD, 0, 0);

    // routed experts
    gateup_bf16_kernel<<<dim3(CAP / 128, II / 128, NE), 256, 0, stream>>>(
        Xg, bWg, bWu, H, CAP, II, DDIM, (long)CAP * DDIM, (long)II * DDIM, (long)CAP * II);
    down_bf16_kernel<1><<<dim3(CAP / 128, DDIM / 128, NE), 256, 0, stream>>>(
        H, bWd, out, tidx, tw, CAP, DDIM, II, (long)CAP * II, (long)DDIM * II);
  } else {
    // fallback: previously-verified fp32-B path
    gather_kernel<<<NE * CAP, 256, 0, stream>>>(x, tidx, Xg);

    gateup_kernel<float><<<dim3(TT / 128, ISD / 128, 1), 256, 0, stream>>>(
        x, Sg, Su, Hs, TT, ISD, DDIM, 0, 0, 0);
    down_kernel<0><<<dim3(TT / 128, DDIM / 128, 1), 256, 0, stream>>>(
        Hs, Sd, out, nullptr, nullptr, TT, DDIM, ISD, 0, 0);

    gateup_kernel<unsigned short><<<dim3(CAP / 128, II / 128, NE), 256, 0, stream>>>(
        Xg, Wg, Wu, H, CAP, II, DDIM, (long)CAP * DDIM, (long)II * DDIM, (long)CAP * II);
    down_kernel<1><<<dim3(CAP / 128, DDIM / 128, NE), 256, 0, stream>>>(
        H, Wd, out, tidx, tw, CAP, DDIM, II, (long)CAP * II, (long)DDIM * II);
  }
}

// Round 2
// 1337.361 us; speedup vs baseline: 1.0318x; 1.0318x over previous
//
#include <hip/hip_runtime.h>
#include <hip/hip_bf16.h>
#include <math.h>

// Problem constants (fixed by the reference)
#define NE   16      // experts
#define DDIM 1024    // embed dim
#define II   4096    // expert intermediate
#define ISD  2048    // shared intermediate
#define TT   4096    // tokens
#define CAP  512     // expert capacity

typedef __attribute__((ext_vector_type(8))) short short8;
typedef __attribute__((ext_vector_type(4))) float floatx4;

static __device__ __forceinline__ unsigned short f2b(float f){
  unsigned int x = __float_as_uint(f);
  return (unsigned short)((x + 0x7fffu + ((x >> 16) & 1u)) >> 16);  // RNE fp32->bf16
}

static __device__ __forceinline__ float gelu_exact(float x){
  return 0.5f * x * (1.0f + erff(x * 0.70710678118654752f));
}

// async 16B global -> LDS (m97 pattern; dest must be wave-uniform base + lane*16)
#define ASYNC_COPY16(gptr, lptr)                                                    \
  __builtin_amdgcn_global_load_lds((const __attribute__((address_space(1))) void*)(gptr), \
                                   (__attribute__((address_space(3))) void*)(lptr), \
                                   16, 0, 0)

// bijective XCD swizzle (T1): consecutive post-swizzle ids land on the same XCD.
static __device__ __forceinline__ int xcd_swizzle(int lid, int nblk){
  if (nblk & 7) return lid;       // only when divisible by 8 (all our grids are)
  const int cpx = nblk >> 3;
  return (lid & 7) * cpx + (lid >> 3);
}

// ---------------- gating: fp64 logits + softmax -> scores (E,T) fp32 ----------------
__global__ void gating_kernel(const float* __restrict__ x, const float* __restrict__ gw,
                              float* __restrict__ scores){
  const int wave = threadIdx.x >> 6, lane = threadIdx.x & 63;
  const int t = blockIdx.x * 4 + wave;
  const float* xp = x + (size_t)t * DDIM;
  float xr[16];
  #pragma unroll
  for (int i = 0; i < 16; i++) xr[i] = xp[i * 64 + lane];
  double logit[NE];
  #pragma unroll
  for (int e = 0; e < NE; e++){
    const float* g = gw + (size_t)e * DDIM;
    double s = 0.0;
    #pragma unroll
    for (int i = 0; i < 16; i++) s += (double)xr[i] * (double)g[i * 64 + lane];
    #pragma unroll
    for (int off = 32; off > 0; off >>= 1) s += __shfl_xor(s, off);
    logit[e] = s;
  }
  double m = logit[0];
  #pragma unroll
  for (int e = 1; e < NE; e++) m = fmax(m, logit[e]);
  double p[NE], sum = 0.0;
  #pragma unroll
  for (int e = 0; e < NE; e++){ p[e] = exp(logit[e] - m); sum += p[e]; }
  if (lane == 0){
    #pragma unroll
    for (int e = 0; e < NE; e++) scores[(size_t)e * TT + t] = (float)(p[e] / sum);
  }
}

// ---------------- top-k by rank counting (matches lax.top_k set semantics) ----------------
__global__ void topk_kernel(const float* __restrict__ scores, int* __restrict__ cnt,
                            int* __restrict__ tidx, float* __restrict__ tw){
  const int e = blockIdx.y;
  __shared__ float s[TT];
  const float* se = scores + (size_t)e * TT;
  for (int i = threadIdx.x; i < TT; i += 256) s[i] = se[i];
  __syncthreads();
  const int t = blockIdx.x * 256 + threadIdx.x;
  const float ms = s[t];
  int r = 0;
  const float4* s4 = reinterpret_cast<const float4*>(s);
  for (int j = 0; j < TT / 4; j++){
    float4 v = s4[j];
    int b = j * 4;
    r += (v.x > ms) || (v.x == ms && (b + 0) < t);
    r += (v.y > ms) || (v.y == ms && (b + 1) < t);
    r += (v.z > ms) || (v.z == ms && (b + 2) < t);
    r += (v.w > ms) || (v.w == ms && (b + 3) < t);
  }
  if (r < CAP){
    int p = atomicAdd(&cnt[e], 1);
    tidx[e * CAP + p] = t;
    tw[e * CAP + p]   = ms;
  }
}

// ---------------- fp32 -> bf16 bulk convert (memory-bound, vectorized) ----------------
__global__ void cvt_bf16_kernel(const float* __restrict__ src, unsigned short* __restrict__ dst,
                                int n4){
  int i = blockIdx.x * 256 + threadIdx.x;
  const int stride = gridDim.x * 256;
  const float4* s = reinterpret_cast<const float4*>(src);
  ushort4* d = reinterpret_cast<ushort4*>(dst);
  for (; i < n4; i += stride){
    float4 v = s[i];
    ushort4 o; o.x = f2b(v.x); o.y = f2b(v.y); o.z = f2b(v.z); o.w = f2b(v.w);
    d[i] = o;
  }
}

// ---------------- gather selected token rows (bf16 source) ----------------
__global__ void gather_b16_kernel(const unsigned short* __restrict__ xb,
                                  const int* __restrict__ tidx,
                                  unsigned short* __restrict__ Xg){
  const int ec = blockIdx.x;                 // 0 .. E*CAP-1
  const int tok = tidx[ec];
  const ushort4* src = reinterpret_cast<const ushort4*>(xb + (size_t)tok * DDIM);
  ushort4* dst = reinterpret_cast<ushort4*>(Xg + (size_t)ec * DDIM);
  dst[threadIdx.x] = src[threadIdx.x];
}

// ---------------- gather (fp32 source -> bf16), fallback path ----------------
__global__ void gather_kernel(const float* __restrict__ x, const int* __restrict__ tidx,
                              unsigned short* __restrict__ Xg){
  const int ec = blockIdx.x;
  const int tok = tidx[ec];
  const float4* src = reinterpret_cast<const float4*>(x + (size_t)tok * DDIM);
  ushort4* dst = reinterpret_cast<ushort4*>(Xg + (size_t)ec * DDIM);
  float4 v = src[threadIdx.x];
  ushort4 o; o.x = f2b(v.x); o.y = f2b(v.y); o.z = f2b(v.z); o.w = f2b(v.w);
  dst[threadIdx.x] = o;
}

// ================= FAST PATH v2: dbuf + prefetch-before-compute + XCD swizzle =================
// A: flat M x K bf16. Bg/Bu: per-expert N x K bf16 (expert = mtile>>2, stride sB; sB=0 for shared).
// 1D grid = (M/128)*(N/128), m fastest after swizzle. 2-phase min recipe: stage(next) -> compute(cur)
// -> one barrier (compiler emits the vmcnt/lgkm drain there).
__launch_bounds__(256, 2)
__global__ void gateup2_kernel(const unsigned short* __restrict__ A,
                               const unsigned short* __restrict__ Bg,
                               const unsigned short* __restrict__ Bu,
                               unsigned short* __restrict__ Hout,
                               int M, int N, int K, long sB, int nm){
  __shared__ __align__(16) unsigned short As[2][128 * 32];
  __shared__ __align__(16) unsigned short Bgs[2][128 * 32];
  __shared__ __align__(16) unsigned short Bus[2][128 * 32];
  const int tid = threadIdx.x;
  const int swz = xcd_swizzle(blockIdx.x, gridDim.x);
  const int mt = swz % nm, ntile = swz / nm;
  const int bm = mt * 128, bn = ntile * 128;
  Bg += (size_t)(mt >> 2) * sB;            // CAP=512 -> 4 m-tiles per expert
  Bu += (size_t)(mt >> 2) * sB;
  const int lane = tid & 63, wave = tid >> 6;
  const int wr = wave >> 1, wc = wave & 1;
  const int fr = lane & 15, fq = lane >> 4;

  // staging: thread covers dest shorts [tid*8, tid*8+8); rows 0-63 issue 0, rows 64-127 issue 1
  const unsigned short* gA = A  + (size_t)(bm + (tid >> 2)) * K + (tid & 3) * 8;
  const unsigned short* gG = Bg + (size_t)(bn + (tid >> 2)) * K + (tid & 3) * 8;
  const unsigned short* gU = Bu + (size_t)(bn + (tid >> 2)) * K + (tid & 3) * 8;
  const size_t half = (size_t)64 * K;

  floatx4 accG[4][4], accU[4][4];
  const floatx4 z4 = {0.f, 0.f, 0.f, 0.f};
  #pragma unroll
  for (int m = 0; m < 4; m++)
    #pragma unroll
    for (int n = 0; n < 4; n++){ accG[m][n] = z4; accU[m][n] = z4; }

  auto stage = [&](int b, int k0){
    ASYNC_COPY16(gA + k0,        &As[b][tid * 8]);
    ASYNC_COPY16(gA + half + k0, &As[b][tid * 8 + 2048]);
    ASYNC_COPY16(gG + k0,        &Bgs[b][tid * 8]);
    ASYNC_COPY16(gG + half + k0, &Bgs[b][tid * 8 + 2048]);
    ASYNC_COPY16(gU + k0,        &Bus[b][tid * 8]);
    ASYNC_COPY16(gU + half + k0, &Bus[b][tid * 8 + 2048]);
  };

  stage(0, 0);
  __syncthreads();
  int buf = 0;
  for (int k0 = 0; k0 < K; k0 += 32){
    if (k0 + 32 < K) stage(buf ^ 1, k0 + 32);   // prefetch next tile, other buffer
    short8 aF[4], gF[4], uF[4];
    #pragma unroll
    for (int m = 0; m < 4; m++)
      aF[m] = *reinterpret_cast<const short8*>(&As[buf][(wr * 64 + m * 16 + fr) * 32 + fq * 8]);
    #pragma unroll
    for (int n = 0; n < 4; n++){
      gF[n] = *reinterpret_cast<const short8*>(&Bgs[buf][(wc * 64 + n * 16 + fr) * 32 + fq * 8]);
      uF[n] = *reinterpret_cast<const short8*>(&Bus[buf][(wc * 64 + n * 16 + fr) * 32 + fq * 8]);
    }
    #pragma unroll
    for (int m = 0; m < 4; m++)
      #pragma unroll
      for (int n = 0; n < 4; n++){
        accG[m][n] = __builtin_amdgcn_mfma_f32_16x16x32_bf16(aF[m], gF[n], accG[m][n], 0, 0, 0);
        accU[m][n] = __builtin_amdgcn_mfma_f32_16x16x32_bf16(aF[m], uF[n], accU[m][n], 0, 0, 0);
      }
    __syncthreads();                             // drains stage (vmcnt) + reads (lgkm)
    buf ^= 1;
  }
  #pragma unroll
  for (int m = 0; m < 4; m++)
    #pragma unroll
    for (int n = 0; n < 4; n++){
      const int col  = bn + wc * 64 + n * 16 + fr;
      const int row0 = bm + wr * 64 + m * 16 + fq * 4;
      #pragma unroll
      for (int i = 0; i < 4; i++){
        float g = accG[m][n][i], u = accU[m][n][i];
        Hout[(size_t)(row0 + i) * N + col] = f2b(gelu_exact(g) * u);
      }
    }
}

// down v2: A flat MxK bf16 (async), B per-expert NxK fp32 (reg-staged f2b, kills cvt pass).
template<int ATOMIC>
__launch_bounds__(256, 2)
__global__ void down2_kernel(const unsigned short* __restrict__ A, const float* __restrict__ B,
                             float* __restrict__ out, const int* __restrict__ tidx,
                             const float* __restrict__ tw,
                             int M, int N, int K, long sB, int nm){
  __shared__ __align__(16) unsigned short As[2][128 * 32];
  __shared__ __align__(16) unsigned short Bs[2][128 * 32];
  const int tid = threadIdx.x;
  const int swz = xcd_swizzle(blockIdx.x, gridDim.x);
  const int mt = swz % nm, ntile = swz / nm;
  const int bm = mt * 128, bn = ntile * 128;
  B += (size_t)(mt >> 2) * sB;
  const int lane = tid & 63, wave = tid >> 6;
  const int wr = wave >> 1, wc = wave & 1;
  const int fr = lane & 15, fq = lane >> 4;

  const unsigned short* gA = A + (size_t)(bm + (tid >> 2)) * K + (tid & 3) * 8;
  const float* gB = B + (size_t)bn * K;
  const size_t half = (size_t)64 * K;

  floatx4 acc[4][4];
  const floatx4 z4 = {0.f, 0.f, 0.f, 0.f};
  #pragma unroll
  for (int m = 0; m < 4; m++)
    #pragma unroll
    for (int n = 0; n < 4; n++) acc[m][n] = z4;

  auto stageA = [&](int b, int k0){
    ASYNC_COPY16(gA + k0,        &As[b][tid * 8]);
    ASYNC_COPY16(gA + half + k0, &As[b][tid * 8 + 2048]);
  };
  auto stageB = [&](int b, int k0){
    #pragma unroll
    for (int p = 0; p < 4; p++){
      const int row = p * 32 + (tid >> 3);
      const int col = (tid & 7) * 4;
      float4 v = *reinterpret_cast<const float4*>(gB + (size_t)row * K + k0 + col);
      ushort4 o; o.x = f2b(v.x); o.y = f2b(v.y); o.z = f2b(v.z); o.w = f2b(v.w);
      *reinterpret_cast<ushort4*>(&Bs[b][row * 32 + col]) = o;
    }
  };

  stageA(0, 0); stageB(0, 0);
  __syncthreads();
  int buf = 0;
  for (int k0 = 0; k0 < K; k0 += 32){
    if (k0 + 32 < K){ stageA(buf ^ 1, k0 + 32); stageB(buf ^ 1, k0 + 32); }
    short8 aF[4], bF[4];
    #pragma unroll
    for (int m = 0; m < 4; m++)
      aF[m] = *reinterpret_cast<const short8*>(&As[buf][(wr * 64 + m * 16 + fr) * 32 + fq * 8]);
    #pragma unroll
    for (int n = 0; n < 4; n++)
      bF[n] = *reinterpret_cast<const short8*>(&Bs[buf][(wc * 64 + n * 16 + fr) * 32 + fq * 8]);
    #pragma unroll
    for (int m = 0; m < 4; m++)
      #pragma unroll
      for (int n = 0; n < 4; n++)
        acc[m][n] = __builtin_amdgcn_mfma_f32_16x16x32_bf16(aF[m], bF[n], acc[m][n], 0, 0, 0);
    __syncthreads();
    buf ^= 1;
  }
  #pragma unroll
  for (int m = 0; m < 4; m++)
    #pragma unroll
    for (int n = 0; n < 4; n++){
      const int col  = bn + wc * 64 + n * 16 + fr;
      const int row0 = bm + wr * 64 + m * 16 + fq * 4;
      #pragma unroll
      for (int i = 0; i < 4; i++){
        float val = acc[m][n][i];
        if constexpr (ATOMIC){
          const int r = row0 + i;                // global flat row in (E*CAP)
          const int token = tidx[r];
          const float wgt = tw[r];
          atomicAdd(&out[(size_t)token * DDIM + col], val * wgt);
        } else {
          out[(size_t)(row0 + i) * N + col] = val;
        }
      }
    }
}

// ================= FALLBACK PATH (verified previously): fp32-B staging =================
#define LDT 40
template<typename TA>
__launch_bounds__(256, 2)
__global__ void gateup_kernel(const TA* __restrict__ A, const float* __restrict__ Bg,
                              const float* __restrict__ Bu, unsigned short* __restrict__ H,
                              int M, int N, int K, long sA, long sB, long sH){
  __shared__ unsigned short As[128 * LDT];
  __shared__ unsigned short Bgs[128 * LDT];
  __shared__ unsigned short Bus[128 * LDT];
  const int tid = threadIdx.x;
  const int z = blockIdx.z;
  A  += (size_t)z * sA;  Bg += (size_t)z * sB;  Bu += (size_t)z * sB;  H += (size_t)z * sH;
  const int bm = blockIdx.x * 128, bn = blockIdx.y * 128;
  const int lane = tid & 63, wave = tid >> 6;
  const int wr = wave >> 1, wc = wave & 1;
  const int fr = lane & 15, fq = lane >> 4;

  floatx4 accG[4][4], accU[4][4];
  const floatx4 z4 = {0.f, 0.f, 0.f, 0.f};
  #pragma unroll
  for (int m = 0; m < 4; m++)
    #pragma unroll
    for (int n = 0; n < 4; n++){ accG[m][n] = z4; accU[m][n] = z4; }

  for (int k0 = 0; k0 < K; k0 += 32){
    #pragma unroll
    for (int p = 0; p < 4; p++){
      const int row = p * 32 + (tid >> 3);
      const int col = (tid & 7) * 4;
      if constexpr (__is_same(TA, float)){
        float4 v = *reinterpret_cast<const float4*>(A + (size_t)(bm + row) * K + k0 + col);
        ushort4 o; o.x = f2b(v.x); o.y = f2b(v.y); o.z = f2b(v.z); o.w = f2b(v.w);
        *reinterpret_cast<ushort4*>(&As[row * LDT + col]) = o;
      } else {
        *reinterpret_cast<ushort4*>(&As[row * LDT + col]) =
            *reinterpret_cast<const ushort4*>(A + (size_t)(bm + row) * K + k0 + col);
      }
      float4 vg = *reinterpret_cast<const float4*>(Bg + (size_t)(bn + row) * K + k0 + col);
      ushort4 og; og.x = f2b(vg.x); og.y = f2b(vg.y); og.z = f2b(vg.z); og.w = f2b(vg.w);
      *reinterpret_cast<ushort4*>(&Bgs[row * LDT + col]) = og;
      float4 vu = *reinterpret_cast<const float4*>(Bu + (size_t)(bn + row) * K + k0 + col);
      ushort4 ou; ou.x = f2b(vu.x); ou.y = f2b(vu.y); ou.z = f2b(vu.z); ou.w = f2b(vu.w);
      *reinterpret_cast<ushort4*>(&Bus[row * LDT + col]) = ou;
    }
    __syncthreads();
    short8 aF[4], gF[4], uF[4];
    #pragma unroll
    for (int m = 0; m < 4; m++)
      aF[m] = *reinterpret_cast<const short8*>(&As[(wr * 64 + m * 16 + fr) * LDT + fq * 8]);
    #pragma unroll
    for (int n = 0; n < 4; n++){
      gF[n] = *reinterpret_cast<const short8*>(&Bgs[(wc * 64 + n * 16 + fr) * LDT + fq * 8]);
      uF[n] = *reinterpret_cast<const short8*>(&Bus[(wc * 64 + n * 16 + fr) * LDT + fq * 8]);
    }
    #pragma unroll
    for (int m = 0; m < 4; m++)
      #pragma unroll
      for (int n = 0; n < 4; n++){
        accG[m][n] = __builtin_amdgcn_mfma_f32_16x16x32_bf16(aF[m], gF[n], accG[m][n], 0, 0, 0);
        accU[m][n] = __builtin_amdgcn_mfma_f32_16x16x32_bf16(aF[m], uF[n], accU[m][n], 0, 0, 0);
      }
    __syncthreads();
  }
  #pragma unroll
  for (int m = 0; m < 4; m++)
    #pragma unroll
    for (int n = 0; n < 4; n++){
      const int col  = bn + wc * 64 + n * 16 + fr;
      const int row0 = bm + wr * 64 + m * 16 + fq * 4;
      #pragma unroll
      for (int i = 0; i < 4; i++){
        float g = accG[m][n][i], u = accU[m][n][i];
        H[(size_t)(row0 + i) * N + col] = f2b(gelu_exact(g) * u);
      }
    }
}

template<int ATOMIC>
__launch_bounds__(256, 2)
__global__ void down_kernel(const unsigned short* __restrict__ A, const float* __restrict__ B,
                            float* __restrict__ out, const int* __restrict__ tidx,
                            const float* __restrict__ tw,
                            int M, int N, int K, long sA, long sB){
  __shared__ unsigned short As[128 * LDT];
  __shared__ unsigned short Bs[128 * LDT];
  const int tid = threadIdx.x;
  const int z = blockIdx.z;
  A += (size_t)z * sA;  B += (size_t)z * sB;
  const int bm = blockIdx.x * 128, bn = blockIdx.y * 128;
  const int lane = tid & 63, wave = tid >> 6;
  const int wr = wave >> 1, wc = wave & 1;
  const int fr = lane & 15, fq = lane >> 4;

  floatx4 acc[4][4];
  const floatx4 z4 = {0.f, 0.f, 0.f, 0.f};
  #pragma unroll
  for (int m = 0; m < 4; m++)
    #pragma unroll
    for (int n = 0; n < 4; n++) acc[m][n] = z4;

  for (int k0 = 0; k0 < K; k0 += 32){
    #pragma unroll
    for (int p = 0; p < 4; p++){
      const int row = p * 32 + (tid >> 3);
      const int col = (tid & 7) * 4;
      *reinterpret_cast<ushort4*>(&As[row * LDT + col]) =
          *reinterpret_cast<const ushort4*>(A + (size_t)(bm + row) * K + k0 + col);
      float4 v = *reinterpret_cast<const float4*>(B + (size_t)(bn + row) * K + k0 + col);
      ushort4 o; o.x = f2b(v.x); o.y = f2b(v.y); o.z = f2b(v.z); o.w = f2b(v.w);
      *reinterpret_cast<ushort4*>(&Bs[row * LDT + col]) = o;
    }
    __syncthreads();
    short8 aF[4], bF[4];
    #pragma unroll
    for (int m = 0; m < 4; m++)
      aF[m] = *reinterpret_cast<const short8*>(&As[(wr * 64 + m * 16 + fr) * LDT + fq * 8]);
    #pragma unroll
    for (int n = 0; n < 4; n++)
      bF[n] = *reinterpret_cast<const short8*>(&Bs[(wc * 64 + n * 16 + fr) * LDT + fq * 8]);
    #pragma unroll
    for (int m = 0; m < 4; m++)
      #pragma unroll
      for (int n = 0; n < 4; n++)
        acc[m][n] = __builtin_amdgcn_mfma_f32_16x16x32_bf16(aF[m], bF[n], acc[m][n], 0, 0, 0);
    __syncthreads();
  }
  #pragma unroll
  for (int m = 0; m < 4; m++)
    #pragma unroll
    for (int n = 0; n < 4; n++){
      const int col  = bn + wc * 64 + n * 16 + fr;
      const int row0 = bm + wr * 64 + m * 16 + fq * 4;
      #pragma unroll
      for (int i = 0; i < 4; i++){
        float val = acc[m][n][i];
        if constexpr (ATOMIC){
          const int r = row0 + i;
          const int token = tidx[z * CAP + r];
          const float wgt = tw[z * CAP + r];
          atomicAdd(&out[(size_t)token * DDIM + col], val * wgt);
        } else {
          out[(size_t)(row0 + i) * N + col] = val;
        }
      }
    }
}

extern "C" void kernel_launch(void* const* d_in, const int* in_sizes, int n_in,
                              void* d_out, int out_size, void* d_ws, size_t ws_size,
                              hipStream_t stream){
  const float* x  = (const float*)d_in[0];
  const float* gw = (const float*)d_in[1];
  const float* Wg = (const float*)d_in[2];
  const float* Wu = (const float*)d_in[3];
  const float* Wd = (const float*)d_in[4];
  const float* Sg = (const float*)d_in[5];
  const float* Su = (const float*)d_in[6];
  const float* Sd = (const float*)d_in[7];
  float* out = (float*)d_out;

  char* w = (char*)d_ws;
  float* scores        = (float*)w;           w += (size_t)NE * TT * 4;
  int*   cnt           = (int*)w;             w += 256;
  int*   tidx          = (int*)w;             w += (size_t)NE * CAP * 4;
  float* tw            = (float*)w;           w += (size_t)NE * CAP * 4;
  unsigned short* Xg   = (unsigned short*)w;  w += (size_t)NE * CAP * DDIM * 2;
  unsigned short* H    = (unsigned short*)w;  w += (size_t)NE * CAP * II * 2;
  unsigned short* Hs   = (unsigned short*)w;  w += (size_t)TT * ISD * 2;

  const size_t base_used = (size_t)(w - (char*)d_ws);
  const size_t need_extra = (size_t)TT * DDIM * 2           // xb
                          + (size_t)NE * II * DDIM * 2 * 2  // bWg, bWu
                          + (size_t)ISD * DDIM * 2 * 2;     // bSg, bSu
  const bool fast = (base_used + need_extra) <= ws_size;    // ~365 MB total

  hipMemsetAsync(cnt, 0, NE * sizeof(int), stream);
  gating_kernel<<<TT / 4, 256, 0, stream>>>(x, gw, scores);
  topk_kernel<<<dim3(TT / 256, NE), 256, 0, stream>>>(scores, cnt, tidx, tw);

  if (fast){
    unsigned short* xb  = (unsigned short*)w;  w += (size_t)TT * DDIM * 2;
    unsigned short* bWg = (unsigned short*)w;  w += (size_t)NE * II * DDIM * 2;
    unsigned short* bWu = (unsigned short*)w;  w += (size_t)NE * II * DDIM * 2;
    unsigned short* bSg = (unsigned short*)w;  w += (size_t)ISD * DDIM * 2;
    unsigned short* bSu = (unsigned short*)w;  w += (size_t)ISD * DDIM * 2;

    // one-time fp32 -> bf16 conversion (Wd/Sd now converted in-kernel by down2)
    cvt_bf16_kernel<<<1024, 256, 0, stream>>>(x,  xb,  TT * DDIM / 4);
    cvt_bf16_kernel<<<2048, 256, 0, stream>>>(Wg, bWg, NE * II * DDIM / 4);
    cvt_bf16_kernel<<<2048, 256, 0, stream>>>(Wu, bWu, NE * II * DDIM / 4);
    cvt_bf16_kernel<<<512, 256, 0, stream>>>(Sg, bSg, ISD * DDIM / 4);
    cvt_bf16_kernel<<<512, 256, 0, stream>>>(Su, bSu, ISD * DDIM / 4);

    gather_b16_kernel<<<NE * CAP, 256, 0, stream>>>(xb, tidx, Xg);

    // shared experts: Hs = gelu(xb Sg^T) * (xb Su^T); out = Hs Sd^T
    gateup2_kernel<<<(TT / 128) * (ISD / 128), 256, 0, stream>>>(
        xb, bSg, bSu, Hs, TT, ISD, DDIM, 0L, TT / 128);
    down2_kernel<0><<<(TT / 128) * (DDIM / 128), 256, 0, stream>>>(
        Hs, Sd, out, nullptr, nullptr, TT, DDIM, ISD, 0L, TT / 128);

    // routed experts: H = gelu(Xg Wg^T) * (Xg Wu^T); out += w * (H Wd^T)
    gateup2_kernel<<<(NE * CAP / 128) * (II / 128), 256, 0, stream>>>(
        Xg, bWg, bWu, H, NE * CAP, II, DDIM, (long)II * DDIM, NE * CAP / 128);
    down2_kernel<1><<<(NE * CAP / 128) * (DDIM / 128), 256, 0, stream>>>(
        H, Wd, out, tidx, tw, NE * CAP, DDIM, II, (long)DDIM * II, NE * CAP / 128);
  } else {
    // fallback: previously-verified fp32-B path
    gather_kernel<<<NE * CAP, 256, 0, stream>>>(x, tidx, Xg);

    gateup_kernel<float><<<dim3(TT / 128, ISD / 128, 1), 256, 0, stream>>>(
        x, Sg, Su, Hs, TT, ISD, DDIM, 0, 0, 0);
    down_kernel<0><<<dim3(TT / 128, DDIM / 128, 1), 256, 0, stream>>>(
        Hs, Sd, out, nullptr, nullptr, TT, DDIM, ISD, 0, 0);

    gateup_kernel<unsigned short><<<dim3(CAP / 128, II / 128, NE), 256, 0, stream>>>(
        Xg, Wg, Wu, H, CAP, II, DDIM, (long)CAP * DDIM, (long)II * DDIM, (long)CAP * II);
    down_kernel<1><<<dim3(CAP / 128, DDIM / 128, NE), 256, 0, stream>>>(
        H, Wd, out, tidx, tw, CAP, DDIM, II, (long)CAP * II, (long)DDIM * II);
  }
}